// Round 16
// baseline (165.208 us; speedup 1.0000x reference)
//
#include <hip/hip_runtime.h>
#include <hip/hip_bf16.h>
#include <cstdint>

using bf16   = __bf16;
using bf16x4 = __attribute__((ext_vector_type(4))) __bf16;
using bf16x8 = __attribute__((ext_vector_type(8))) __bf16;
using f32x4  = __attribute__((ext_vector_type(4))) float;

#define MFMA16(a, b, c) __builtin_amdgcn_mfma_f32_16x16x32_bf16((a), (b), (c), 0, 0, 0)

// async global->LDS, 16B per lane; LDS dest = wave-uniform base + lane*16.
// CONTRACT (R7): staging bounded by __syncthreads on both sides.
// CONTRACT (R3/R12): no scheme holding >=32 extra live VGPRs ACROSS a compute
// phase — spills. Transients that die within a phase are fine.
// LESSON (R16, from m169): don't LDS-stage data that is L2-resident and read
// once per consumer — K is read directly from global (XCD-local L2).
__device__ __forceinline__ void load_lds16(const bf16* g, bf16* l) {
    __builtin_amdgcn_global_load_lds(
        (const __attribute__((address_space(1))) void*)g,
        (__attribute__((address_space(3))) void*)l, 16, 0, 0);
}

// ---------------- fused cast fp32 -> bf16 (x, Wq*scale, Wk, Wv) ----------------
__global__ __launch_bounds__(256) void cast_all(const float* __restrict__ x,
                                                const float* __restrict__ Wq,
                                                const float* __restrict__ Wk,
                                                const float* __restrict__ Wv,
                                                bf16* __restrict__ xb,
                                                bf16* __restrict__ wb,
                                                float qscale) {
    int i = blockIdx.x * 256 + threadIdx.x;   // float4 index, 1835008 total
    const float* src; bf16* dst; int off; float scale = 1.0f;
    if (i < 1048576)      { src = x;  dst = xb;              off = i; }
    else if (i < 1310720) { src = Wq; dst = wb;              off = i - 1048576; scale = qscale; }
    else if (i < 1572864) { src = Wk; dst = wb + (1u << 20); off = i - 1310720; }
    else                  { src = Wv; dst = wb + (2u << 20); off = i - 1572864; }
    float4 v = reinterpret_cast<const float4*>(src)[off];
    bf16x4 o;
    o[0] = (bf16)(v.x * scale); o[1] = (bf16)(v.y * scale);
    o[2] = (bf16)(v.z * scale); o[3] = (bf16)(v.w * scale);
    reinterpret_cast<bf16x4*>(dst)[off] = o;
}

// ---------------- fused QKV projection: y = x @ [Wq|Wk|Wv]^T ----------------
// R14 kernel (verified, part of 153.1 best): 128x128 m97 structure,
// XCD-affinity remap, LDS epilogue with coalesced bf16x8 stores.
__global__ __launch_bounds__(256) void qkv_gemm(const bf16* __restrict__ xb,
                                                const bf16* __restrict__ wb,
                                                bf16* __restrict__ Qo,
                                                bf16* __restrict__ Ko,
                                                bf16* __restrict__ Vt) {
    const int id  = blockIdx.x;        // 0..767
    const int xcd = id & 7;
    const int r   = id >> 3;           // 0..95
    const int ntile = r >> 2;          // 0..23  (n-major within XCD)
    const int ms    = r & 3;           // 0..3
    const int mtile = xcd * 4 + ms;    // 0..31
    const int n0 = ntile * 128;
    const int m0 = mtile * 128;

    __shared__ __align__(16) bf16 SM[128 * 132];
    bf16* const As = SM;               // 128*64
    bf16* const Bs = SM + 128 * 64;    // 128*64

    const int t    = threadIdx.x;
    const int lane = t & 63;
    const int wid  = t >> 6;
    const int quad = lane >> 4;
    const int col  = lane & 15;
    const int wm   = wid & 1;      // M half (64)
    const int wn   = wid >> 1;     // N half (64)

    const int rsub = lane >> 3;
    const int csw  = ((lane & 7) ^ rsub) * 8;

    f32x4 acc[4][4] = {};

    const bf16* Ag = &xb[(size_t)(m0 + rsub) * 1024 + csw];
    const bf16* Bg = &wb[(size_t)(n0 + rsub) * 1024 + csw];

    for (int kc = 0; kc < 1024; kc += 64) {
        __syncthreads();
#pragma unroll
        for (int j = 0; j < 4; ++j) {
            const int c = wid * 4 + j;
            load_lds16(Ag + kc + (size_t)c * 8 * 1024, &As[c * 512]);
        }
#pragma unroll
        for (int j = 0; j < 4; ++j) {
            const int c = wid * 4 + j;
            load_lds16(Bg + kc + (size_t)c * 8 * 1024, &Bs[c * 512]);
        }
        __syncthreads();

#pragma unroll
        for (int ks = 0; ks < 2; ++ks) {
            const int ca = ((ks * 4 + quad) ^ (col & 7)) * 8;
            bf16x8 a[4], b[4];
#pragma unroll
            for (int i = 0; i < 4; ++i)
                a[i] = *reinterpret_cast<const bf16x8*>(
                    &As[(wm * 64 + i * 16 + col) * 64 + ca]);
#pragma unroll
            for (int i = 0; i < 4; ++i)
                b[i] = *reinterpret_cast<const bf16x8*>(
                    &Bs[(wn * 64 + i * 16 + col) * 64 + ca]);
#pragma unroll
            for (int mt = 0; mt < 4; ++mt)
#pragma unroll
                for (int nt = 0; nt < 4; ++nt)
                    acc[mt][nt] = MFMA16(a[mt], b[nt], acc[mt][nt]);
        }
    }

    const int w = ntile >> 3;   // 0=Q 1=K 2=V
    __syncthreads();
    if (w == 2) {
#pragma unroll
        for (int mt = 0; mt < 4; ++mt)
#pragma unroll
            for (int nt = 0; nt < 4; ++nt)
#pragma unroll
                for (int r2 = 0; r2 < 4; ++r2) {
                    int s_local = wm * 64 + mt * 16 + quad * 4 + r2;
                    int n_local = wn * 64 + nt * 16 + col;
                    SM[n_local * 132 + s_local] = (bf16)acc[mt][nt][r2];
                }
    } else {
#pragma unroll
        for (int mt = 0; mt < 4; ++mt)
#pragma unroll
            for (int nt = 0; nt < 4; ++nt)
#pragma unroll
                for (int r2 = 0; r2 < 4; ++r2) {
                    int m_local = wm * 64 + mt * 16 + quad * 4 + r2;
                    int n_local = wn * 64 + nt * 16 + col;
                    SM[m_local * 132 + n_local] = (bf16)acc[mt][nt][r2];
                }
    }
    __syncthreads();

    const int sbase = m0 & 2047;
    const int bb16  = (m0 >> 11) * 16;
    if (w == 2) {
#pragma unroll
        for (int i = 0; i < 8; ++i) {
            int task = i * 256 + t;
            int row = task >> 4, ch = task & 15;
            int n1 = (n0 + row) & 1023;
            int hh = n1 >> 6, dd = n1 & 63;
            bf16x8 v = *reinterpret_cast<const bf16x8*>(&SM[row * 132 + ch * 8]);
            *reinterpret_cast<bf16x8*>(
                &Vt[((size_t)(bb16 + hh) * 64 + dd) * 2048 + sbase + ch * 8]) = v;
        }
    } else {
        bf16* const dst = (w == 0) ? Qo : Ko;
#pragma unroll
        for (int i = 0; i < 8; ++i) {
            int task = i * 256 + t;
            int row = task >> 4, ch = task & 15;
            int n1 = (n0 + ch * 8) & 1023;
            int hh = n1 >> 6, dd = n1 & 63;
            bf16x8 v = *reinterpret_cast<const bf16x8*>(&SM[row * 132 + ch * 8]);
            *reinterpret_cast<bf16x8*>(
                &dst[((size_t)(bb16 + hh) * 2048 + sbase + row) * 64 + dd]) = v;
        }
    }
}

// ---------------- V suffix tile sums (parallel, 256 blocks) ----------------
__global__ __launch_bounds__(256) void tail_kernel(const bf16* __restrict__ Vt,
                                                   float* __restrict__ Tail) {
    const int bh = blockIdx.x >> 3;
    const int dg = blockIdx.x & 7;
    const bf16* Vg = Vt + (size_t)bh * 64 * 2048 + (size_t)dg * 8 * 2048;
    float* Tg = Tail + (size_t)bh * 33 * 64 + dg * 8;

    __shared__ float ts[8 * 33];
    const int tid = threadIdx.x;
    const int d  = tid >> 5;
    const int tt = tid & 31;

    const bf16* p = &Vg[(size_t)d * 2048 + tt * 64];
    float s = 0.0f;
#pragma unroll
    for (int j = 0; j < 8; ++j) {
        bf16x8 v = *reinterpret_cast<const bf16x8*>(p + j * 8);
#pragma unroll
        for (int e = 0; e < 8; ++e) s += (float)v[e];
    }
    ts[d * 33 + tt] = s;
    __syncthreads();

    if (tid < 8) {
        const int dd = tid;
        float acc = 0.0f;
        Tg[32 * 64 + dd] = 0.0f;
        for (int t2 = 31; t2 >= 1; --t2) {
            acc += ts[dd * 33 + t2];
            Tg[t2 * 64 + dd] = acc;
        }
    }
}

// ---------------- attention ----------------
// R13 barrier skeleton EXACTLY, with K read DIRECT from global (XCD-local L2)
// instead of LDS staging (m169 precedent: L2-fit data staged once-per-use is
// pure overhead). kb[2][4] loads issue at loop-top and complete under the
// V-stage drain barrier (compiler emits vmcnt(0) before s_barrier) — latency
// fully hidden; transients die inside the QK phase (no R12-class spill).
// LDS: Vs 16KB + shared Ps 17KB = 33 KB. Only V uses global_load_lds.
__global__ __launch_bounds__(256) void attn_kernel(const bf16* __restrict__ Q,
                                                   const bf16* __restrict__ K,
                                                   const bf16* __restrict__ Vt,
                                                   const float* __restrict__ Tail,
                                                   float* __restrict__ out) {
    const int bid  = blockIdx.x;          // 0..511
    const int work = (bid & 7) * 64 + (bid >> 3);
    const int bh   = work >> 4;           // 0..31, 4 bh per XCD
    const int x    = work & 15;           // pair index
    const int b    = bh >> 4;
    const int h    = bh & 15;

    const int t    = threadIdx.x;
    const int lane = t & 63;
    const int wid  = t >> 6;
    const int quad = lane >> 4;
    const int col  = lane & 15;
    const int qh   = wid & 1;     // q-half (32 rows) for both phases
    const int kh   = wid >> 1;    // key-half (QK) / d-half (PV)

    const bf16* Qg = Q + (size_t)bh * 2048 * 64;
    const bf16* Kg = K + (size_t)bh * 2048 * 64;
    const bf16* Vg = Vt + (size_t)bh * 64 * 2048;

    __shared__ __align__(16) bf16 Vs[64 * 128];   // 16 KB: [d][key], swizzled
    __shared__ __align__(16) bf16 Ps[64 * 136];   // 17 KB: [q][key], shared

    bf16x8 ones;
#pragma unroll
    for (int i = 0; i < 8; ++i) ones[i] = (bf16)1.0f;

    // V staging: 16 chunk-blocks of 4 rows x 128
    const int rV    = lane >> 4;
    const int ccV   = lane & 15;

    for (int pp = 0; pp < 2; ++pp) {
        const int qt = pp == 0 ? (31 - x) : x;
        const int q0 = qt * 64;
        const int np = (qt >> 1) + 1;      // 128-key chunks to process in-loop

        // Q frags: qf[qs][ks] for the wave's 2 q-subtiles
        bf16x8 qf[2][2];
#pragma unroll
        for (int qs = 0; qs < 2; ++qs)
#pragma unroll
            for (int ks = 0; ks < 2; ++ks)
                qf[qs][ks] = *reinterpret_cast<const bf16x8*>(
                    &Qg[(size_t)(q0 + qh * 32 + qs * 16 + col) * 64 + ks * 32 + quad * 8]);

        // init with fully-masked tail beyond 2*np tiles (p == 1 there)
        f32x4 o[2][2];
        f32x4 la[2];
        {
            const float tc = 64.0f * (float)(32 - 2 * np);
#pragma unroll
            for (int qs = 0; qs < 2; ++qs)
#pragma unroll
                for (int r = 0; r < 4; ++r) la[qs][r] = tc;
            const float* Tg = Tail + ((size_t)bh * 33 + 2 * np) * 64;
#pragma unroll
            for (int dt = 0; dt < 2; ++dt) {
                float tv = Tg[kh * 32 + dt * 16 + col];
#pragma unroll
                for (int qs = 0; qs < 2; ++qs)
#pragma unroll
                    for (int r = 0; r < 4; ++r) o[qs][dt][r] = tv;
            }
        }

        const int s0max = (np - 1) * 128;

        for (int s0 = 0; s0 < np * 128; s0 += 128) {
            // K fragments direct from global (L2-resident via XCD remap);
            // issued before the barriers so the stage-drain hides the latency.
            bf16x8 kb[2][4];
#pragma unroll
            for (int ks = 0; ks < 2; ++ks)
#pragma unroll
                for (int nt = 0; nt < 4; ++nt)
                    kb[ks][nt] = *reinterpret_cast<const bf16x8*>(
                        &Kg[(size_t)(s0 + (kh * 4 + nt) * 16 + col) * 64 +
                            ks * 32 + quad * 8]);

            __syncthreads();   // previous chunk's Vs/Ps reads complete
#pragma unroll
            for (int jj = 0; jj < 4; ++jj) {
                const int c = wid * 4 + jj;
                const int d = c * 4 + rV;
                load_lds16(&Vg[(size_t)d * 2048 + s0 + ((ccV ^ (d & 15)) * 8)],
                           &Vs[c * 512]);
            }
            __syncthreads();   // V staged + kb loads drained (vmcnt(0))

            // QK (swapped): S^T for keys [kh*64..+64) x q [qh*32..+32)
            // sv[qs][nt][r] = S[key=s0+kh*64+nt*16+quad*4+r][q=q0+qh*32+qs*16+col]
            f32x4 sv[2][4] = {};
            __builtin_amdgcn_s_setprio(1);
#pragma unroll
            for (int ks = 0; ks < 2; ++ks)
#pragma unroll
                for (int nt = 0; nt < 4; ++nt) {
                    sv[0][nt] = MFMA16(kb[ks][nt], qf[0][ks], sv[0][nt]);
                    sv[1][nt] = MFMA16(kb[ks][nt], qf[1][ks], sv[1][nt]);
                }
            __builtin_amdgcn_s_setprio(0);

            // multiplicative mask only on the last chunk (diagonal + dead upper)
            if (s0 == s0max) {
#pragma unroll
                for (int qs = 0; qs < 2; ++qs) {
                    const int qc = q0 + qh * 32 + qs * 16 + col;
#pragma unroll
                    for (int nt = 0; nt < 4; ++nt)
#pragma unroll
                        for (int r = 0; r < 4; ++r) {
                            int kidx = s0 + kh * 64 + nt * 16 + quad * 4 + r;
                            if (kidx > qc) sv[qs][nt][r] = 0.0f;
                        }
                }
            }

            // exp2 + pack 4 consecutive keys -> ds_write_b64 into shared P [q][key]
#pragma unroll
            for (int qs = 0; qs < 2; ++qs) {
                bf16* Pq = &Ps[(qh * 32 + qs * 16 + col) * 136 + kh * 64];
#pragma unroll
                for (int nt = 0; nt < 4; ++nt) {
                    bf16x4 pw;
#pragma unroll
                    for (int r = 0; r < 4; ++r)
                        pw[r] = (bf16)__builtin_amdgcn_exp2f(sv[qs][nt][r]);
                    *reinterpret_cast<bf16x4*>(&Pq[nt * 16 + quad * 4]) = pw;
                }
            }

            __syncthreads();   // P quadrants from all waves visible

            // PV: o[q-half qh][d-half kh] over all 128 keys; vb shared by 2 q-subs
            __builtin_amdgcn_s_setprio(1);
#pragma unroll
            for (int kg = 0; kg < 4; ++kg) {
                bf16x8 pa0 = *reinterpret_cast<const bf16x8*>(
                    &Ps[(qh * 32 + col) * 136 + kg * 32 + quad * 8]);
                bf16x8 pa1 = *reinterpret_cast<const bf16x8*>(
                    &Ps[(qh * 32 + 16 + col) * 136 + kg * 32 + quad * 8]);
                la[0] = MFMA16(pa0, ones, la[0]);
                la[1] = MFMA16(pa1, ones, la[1]);
#pragma unroll
                for (int dt = 0; dt < 2; ++dt) {
                    bf16x8 vb = *reinterpret_cast<const bf16x8*>(
                        &Vs[(kh * 32 + dt * 16 + col) * 128 + ((kg * 4 + quad) ^ col) * 8]);
                    o[0][dt] = MFMA16(pa0, vb, o[0][dt]);
                    o[1][dt] = MFMA16(pa1, vb, o[1][dt]);
                }
            }
            __builtin_amdgcn_s_setprio(0);
        }

#pragma unroll
        for (int qs = 0; qs < 2; ++qs) {
#pragma unroll
            for (int r = 0; r < 4; ++r) {
                int q = q0 + qh * 32 + qs * 16 + quad * 4 + r;
                float inv = __builtin_amdgcn_rcpf(la[qs][r]);
#pragma unroll
                for (int dt = 0; dt < 2; ++dt) {
                    int d = kh * 32 + dt * 16 + col;
                    out[((size_t)b * 2048 + q) * 1024 + h * 64 + d] = o[qs][dt][r] * inv;
                }
            }
        }
    }
}

extern "C" void kernel_launch(void* const* d_in, const int* in_sizes, int n_in,
                              void* d_out, int out_size, void* d_ws, size_t ws_size,
                              hipStream_t stream) {
    const float* x  = (const float*)d_in[0];
    const float* Wq = (const float*)d_in[1];
    const float* Wk = (const float*)d_in[2];
    const float* Wv = (const float*)d_in[3];
    float* out = (float*)d_out;

    char* ws = (char*)d_ws;
    bf16*  xb   = (bf16*)(ws);                        // 8 MB
    bf16*  wb   = (bf16*)(ws + (size_t)(8  << 20));   // 6 MB [Wq|Wk|Wv]
    bf16*  Qb   = (bf16*)(ws + (size_t)(14 << 20));   // 8 MB [B,H,S,D] (pre-scaled)
    bf16*  Kb   = (bf16*)(ws + (size_t)(22 << 20));   // 8 MB [B,H,S,D]
    bf16*  Vtb  = (bf16*)(ws + (size_t)(30 << 20));   // 8 MB [B,H,D,S]
    float* Tail = (float*)(ws + (size_t)(38 << 20));  // 264 KB

    const float QSCALE = 1.44269504088896f / 32.0f;   // log2(e)/sqrt(E)

    cast_all<<<7168, 256, 0, stream>>>(x, Wq, Wk, Wv, xb, wb, QSCALE);

    qkv_gemm<<<768, 256, 0, stream>>>(xb, wb, Qb, Kb, Vtb);

    tail_kernel<<<256, 256, 0, stream>>>(Vtb, Tail);

    attn_kernel<<<512, 256, 0, stream>>>(Qb, Kb, Vtb, Tail, out);
}

// Round 17
// 152.295 us; speedup vs baseline: 1.0848x; 1.0848x over previous
//
#include <hip/hip_runtime.h>
#include <hip/hip_bf16.h>
#include <cstdint>

using bf16   = __bf16;
using bf16x4 = __attribute__((ext_vector_type(4))) __bf16;
using bf16x8 = __attribute__((ext_vector_type(8))) __bf16;
using f32x4  = __attribute__((ext_vector_type(4))) float;

#define MFMA16(a, b, c) __builtin_amdgcn_mfma_f32_16x16x32_bf16((a), (b), (c), 0, 0, 0)

// async global->LDS, 16B per lane; LDS dest = wave-uniform base + lane*16.
// CONTRACT (R7): staging bounded by __syncthreads on both sides.
// CONTRACT (R3/R12): no scheme holding >=32 extra live VGPRs across a compute
// phase — spills (WRITE_SIZE explosion).
// CONTRACT (R16): keep K in LDS — direct-from-L2 K reads put VMEM latency on
// the critical path (+18%); LDS staging amortizes it across waves.
__device__ __forceinline__ void load_lds16(const bf16* g, bf16* l) {
    __builtin_amdgcn_global_load_lds(
        (const __attribute__((address_space(1))) void*)g,
        (__attribute__((address_space(3))) void*)l, 16, 0, 0);
}

// ---------------- fused cast fp32 -> bf16 (x, Wq*scale, Wk, Wv) ----------------
__global__ __launch_bounds__(256) void cast_all(const float* __restrict__ x,
                                                const float* __restrict__ Wq,
                                                const float* __restrict__ Wk,
                                                const float* __restrict__ Wv,
                                                bf16* __restrict__ xb,
                                                bf16* __restrict__ wb,
                                                float qscale) {
    int i = blockIdx.x * 256 + threadIdx.x;   // float4 index, 1835008 total
    const float* src; bf16* dst; int off; float scale = 1.0f;
    if (i < 1048576)      { src = x;  dst = xb;              off = i; }
    else if (i < 1310720) { src = Wq; dst = wb;              off = i - 1048576; scale = qscale; }
    else if (i < 1572864) { src = Wk; dst = wb + (1u << 20); off = i - 1310720; }
    else                  { src = Wv; dst = wb + (2u << 20); off = i - 1572864; }
    float4 v = reinterpret_cast<const float4*>(src)[off];
    bf16x4 o;
    o[0] = (bf16)(v.x * scale); o[1] = (bf16)(v.y * scale);
    o[2] = (bf16)(v.z * scale); o[3] = (bf16)(v.w * scale);
    reinterpret_cast<bf16x4*>(dst)[off] = o;
}

// ---------------- fused QKV projection: y = x @ [Wq|Wk|Wv]^T ----------------
// 128x128 tiles (m97 structure), BK=64, acc 4x4/wave, XCD-affinity remap
// (R11-verified). LDS epilogue with coalesced bf16x8 stores for all outputs
// (V transposed [n][m] — R12-verified; Q/K staged [m][n] — R14, neutral but
// kept as part of the 153.1 best).
__global__ __launch_bounds__(256) void qkv_gemm(const bf16* __restrict__ xb,
                                                const bf16* __restrict__ wb,
                                                bf16* __restrict__ Qo,
                                                bf16* __restrict__ Ko,
                                                bf16* __restrict__ Vt) {
    const int id  = blockIdx.x;        // 0..767
    const int xcd = id & 7;
    const int r   = id >> 3;           // 0..95
    const int ntile = r >> 2;          // 0..23  (n-major within XCD)
    const int ms    = r & 3;           // 0..3
    const int mtile = xcd * 4 + ms;    // 0..31
    const int n0 = ntile * 128;
    const int m0 = mtile * 128;

    __shared__ __align__(16) bf16 SM[128 * 132];
    bf16* const As = SM;               // 128*64
    bf16* const Bs = SM + 128 * 64;    // 128*64

    const int t    = threadIdx.x;
    const int lane = t & 63;
    const int wid  = t >> 6;
    const int quad = lane >> 4;
    const int col  = lane & 15;
    const int wm   = wid & 1;      // M half (64)
    const int wn   = wid >> 1;     // N half (64)

    const int rsub = lane >> 3;
    const int csw  = ((lane & 7) ^ rsub) * 8;

    f32x4 acc[4][4] = {};

    const bf16* Ag = &xb[(size_t)(m0 + rsub) * 1024 + csw];
    const bf16* Bg = &wb[(size_t)(n0 + rsub) * 1024 + csw];

    for (int kc = 0; kc < 1024; kc += 64) {
        __syncthreads();
#pragma unroll
        for (int j = 0; j < 4; ++j) {
            const int c = wid * 4 + j;
            load_lds16(Ag + kc + (size_t)c * 8 * 1024, &As[c * 512]);
        }
#pragma unroll
        for (int j = 0; j < 4; ++j) {
            const int c = wid * 4 + j;
            load_lds16(Bg + kc + (size_t)c * 8 * 1024, &Bs[c * 512]);
        }
        __syncthreads();

#pragma unroll
        for (int ks = 0; ks < 2; ++ks) {
            const int ca = ((ks * 4 + quad) ^ (col & 7)) * 8;
            bf16x8 a[4], b[4];
#pragma unroll
            for (int i = 0; i < 4; ++i)
                a[i] = *reinterpret_cast<const bf16x8*>(
                    &As[(wm * 64 + i * 16 + col) * 64 + ca]);
#pragma unroll
            for (int i = 0; i < 4; ++i)
                b[i] = *reinterpret_cast<const bf16x8*>(
                    &Bs[(wn * 64 + i * 16 + col) * 64 + ca]);
#pragma unroll
            for (int mt = 0; mt < 4; ++mt)
#pragma unroll
                for (int nt = 0; nt < 4; ++nt)
                    acc[mt][nt] = MFMA16(a[mt], b[nt], acc[mt][nt]);
        }
    }

    const int w = ntile >> 3;   // 0=Q 1=K 2=V
    __syncthreads();
    if (w == 2) {
#pragma unroll
        for (int mt = 0; mt < 4; ++mt)
#pragma unroll
            for (int nt = 0; nt < 4; ++nt)
#pragma unroll
                for (int r2 = 0; r2 < 4; ++r2) {
                    int s_local = wm * 64 + mt * 16 + quad * 4 + r2;
                    int n_local = wn * 64 + nt * 16 + col;
                    SM[n_local * 132 + s_local] = (bf16)acc[mt][nt][r2];
                }
    } else {
#pragma unroll
        for (int mt = 0; mt < 4; ++mt)
#pragma unroll
            for (int nt = 0; nt < 4; ++nt)
#pragma unroll
                for (int r2 = 0; r2 < 4; ++r2) {
                    int m_local = wm * 64 + mt * 16 + quad * 4 + r2;
                    int n_local = wn * 64 + nt * 16 + col;
                    SM[m_local * 132 + n_local] = (bf16)acc[mt][nt][r2];
                }
    }
    __syncthreads();

    const int sbase = m0 & 2047;
    const int bb16  = (m0 >> 11) * 16;
    if (w == 2) {
#pragma unroll
        for (int i = 0; i < 8; ++i) {
            int task = i * 256 + t;
            int row = task >> 4, ch = task & 15;
            int n1 = (n0 + row) & 1023;
            int hh = n1 >> 6, dd = n1 & 63;
            bf16x8 v = *reinterpret_cast<const bf16x8*>(&SM[row * 132 + ch * 8]);
            *reinterpret_cast<bf16x8*>(
                &Vt[((size_t)(bb16 + hh) * 64 + dd) * 2048 + sbase + ch * 8]) = v;
        }
    } else {
        bf16* const dst = (w == 0) ? Qo : Ko;
#pragma unroll
        for (int i = 0; i < 8; ++i) {
            int task = i * 256 + t;
            int row = task >> 4, ch = task & 15;
            int n1 = (n0 + ch * 8) & 1023;
            int hh = n1 >> 6, dd = n1 & 63;
            bf16x8 v = *reinterpret_cast<const bf16x8*>(&SM[row * 132 + ch * 8]);
            *reinterpret_cast<bf16x8*>(
                &dst[((size_t)(bb16 + hh) * 2048 + sbase + row) * 64 + dd]) = v;
        }
    }
}

// ---------------- V suffix tile sums (parallel, 256 blocks) ----------------
__global__ __launch_bounds__(256) void tail_kernel(const bf16* __restrict__ Vt,
                                                   float* __restrict__ Tail) {
    const int bh = blockIdx.x >> 3;
    const int dg = blockIdx.x & 7;
    const bf16* Vg = Vt + (size_t)bh * 64 * 2048 + (size_t)dg * 8 * 2048;
    float* Tg = Tail + (size_t)bh * 33 * 64 + dg * 8;

    __shared__ float ts[8 * 33];
    const int tid = threadIdx.x;
    const int d  = tid >> 5;
    const int tt = tid & 31;

    const bf16* p = &Vg[(size_t)d * 2048 + tt * 64];
    float s = 0.0f;
#pragma unroll
    for (int j = 0; j < 8; ++j) {
        bf16x8 v = *reinterpret_cast<const bf16x8*>(p + j * 8);
#pragma unroll
        for (int e = 0; e < 8; ++e) s += (float)v[e];
    }
    ts[d * 33 + tt] = s;
    __syncthreads();

    if (tid < 8) {
        const int dd = tid;
        float acc = 0.0f;
        Tg[32 * 64 + dd] = 0.0f;
        for (int t2 = 31; t2 >= 1; --t2) {
            acc += ts[dd * 33 + t2];
            Tg[t2 * 64 + dd] = acc;
        }
    }
}

// ---------------- attention ----------------
// R13-EXACT kernel (best measured, under the 42 us fill): 128-key chunks,
// 3 barriers/chunk, 2-way LDS-operand reuse, swapped QK, shared P, paired
// q-tiles qtb=31-x then qta=x (33 uniform tiles/block), XCD-affinity remap
// (FETCH 12.5 MB). K+V staged via global_load_lds, barrier-bounded both
// sides. Nulls/regressions established for this structure: barrier removal
// (R15), Q/K store coalescing (R14), direct-L2 K (R16), reg prefetch (R12),
// 64-key double-buffer (R9).
__global__ __launch_bounds__(256) void attn_kernel(const bf16* __restrict__ Q,
                                                   const bf16* __restrict__ K,
                                                   const bf16* __restrict__ Vt,
                                                   const float* __restrict__ Tail,
                                                   float* __restrict__ out) {
    const int bid  = blockIdx.x;          // 0..511
    const int work = (bid & 7) * 64 + (bid >> 3);
    const int bh   = work >> 4;           // 0..31, 4 bh per XCD
    const int x    = work & 15;           // pair index
    const int b    = bh >> 4;
    const int h    = bh & 15;

    const int t    = threadIdx.x;
    const int lane = t & 63;
    const int wid  = t >> 6;
    const int quad = lane >> 4;
    const int col  = lane & 15;
    const int qh   = wid & 1;     // q-half (32 rows) for both phases
    const int kh   = wid >> 1;    // key-half (QK) / d-half (PV)

    const bf16* Qg = Q + (size_t)bh * 2048 * 64;
    const bf16* Kg = K + (size_t)bh * 2048 * 64;
    const bf16* Vg = Vt + (size_t)bh * 64 * 2048;

    __shared__ __align__(16) bf16 Ks[128 * 64];   // 16 KB: [key][d], swizzled
    __shared__ __align__(16) bf16 Vs[64 * 128];   // 16 KB: [d][key], swizzled
    __shared__ __align__(16) bf16 Ps[64 * 136];   // 17 KB: [q][key], shared

    bf16x8 ones;
#pragma unroll
    for (int i = 0; i < 8; ++i) ones[i] = (bf16)1.0f;

    // K staging: 16 chunk-blocks of 8 rows x 64; V staging: 16 chunk-blocks of 4 rows x 128
    const int rsubK = lane >> 3;
    const int cswK  = ((lane & 7) ^ rsubK) * 8;
    const int rV    = lane >> 4;
    const int ccV   = lane & 15;

    for (int pp = 0; pp < 2; ++pp) {
        const int qt = pp == 0 ? (31 - x) : x;
        const int q0 = qt * 64;
        const int np = (qt >> 1) + 1;      // 128-key chunks to process in-loop

        // Q frags: qf[qs][ks] for the wave's 2 q-subtiles
        bf16x8 qf[2][2];
#pragma unroll
        for (int qs = 0; qs < 2; ++qs)
#pragma unroll
            for (int ks = 0; ks < 2; ++ks)
                qf[qs][ks] = *reinterpret_cast<const bf16x8*>(
                    &Qg[(size_t)(q0 + qh * 32 + qs * 16 + col) * 64 + ks * 32 + quad * 8]);

        // init with fully-masked tail beyond 2*np tiles (p == 1 there)
        f32x4 o[2][2];
        f32x4 la[2];
        {
            const float tc = 64.0f * (float)(32 - 2 * np);
#pragma unroll
            for (int qs = 0; qs < 2; ++qs)
#pragma unroll
                for (int r = 0; r < 4; ++r) la[qs][r] = tc;
            const float* Tg = Tail + ((size_t)bh * 33 + 2 * np) * 64;
#pragma unroll
            for (int dt = 0; dt < 2; ++dt) {
                float tv = Tg[kh * 32 + dt * 16 + col];
#pragma unroll
                for (int qs = 0; qs < 2; ++qs)
#pragma unroll
                    for (int r = 0; r < 4; ++r) o[qs][dt][r] = tv;
            }
        }

        const int s0max = (np - 1) * 128;

        for (int s0 = 0; s0 < np * 128; s0 += 128) {
            __syncthreads();   // previous phase's LDS reads complete
#pragma unroll
            for (int jj = 0; jj < 4; ++jj) {
                const int c = wid * 4 + jj;
                load_lds16(&Kg[(size_t)(s0 + c * 8 + rsubK) * 64 + cswK], &Ks[c * 512]);
                const int d = c * 4 + rV;
                load_lds16(&Vg[(size_t)d * 2048 + s0 + ((ccV ^ (d & 15)) * 8)], &Vs[c * 512]);
            }
            __syncthreads();   // staging drained (vmcnt(0) before s_barrier)

            // QK (swapped): S^T for keys [kh*64..+64) x q [qh*32..+32)
            // sv[qs][nt][r] = S[key=s0+kh*64+nt*16+quad*4+r][q=q0+qh*32+qs*16+col]
            f32x4 sv[2][4] = {};
            __builtin_amdgcn_s_setprio(1);
#pragma unroll
            for (int ks = 0; ks < 2; ++ks) {
                const int ca = ((ks * 4 + quad) ^ (col & 7)) * 8;
#pragma unroll
                for (int nt = 0; nt < 4; ++nt) {
                    bf16x8 kb = *reinterpret_cast<const bf16x8*>(
                        &Ks[((kh * 4 + nt) * 16 + col) * 64 + ca]);
                    sv[0][nt] = MFMA16(kb, qf[0][ks], sv[0][nt]);
                    sv[1][nt] = MFMA16(kb, qf[1][ks], sv[1][nt]);
                }
            }
            __builtin_amdgcn_s_setprio(0);

            // multiplicative mask only on the last chunk (diagonal + dead upper)
            if (s0 == s0max) {
#pragma unroll
                for (int qs = 0; qs < 2; ++qs) {
                    const int qc = q0 + qh * 32 + qs * 16 + col;
#pragma unroll
                    for (int nt = 0; nt < 4; ++nt)
#pragma unroll
                        for (int r = 0; r < 4; ++r) {
                            int kidx = s0 + kh * 64 + nt * 16 + quad * 4 + r;
                            if (kidx > qc) sv[qs][nt][r] = 0.0f;
                        }
                }
            }

            // exp2 + pack 4 consecutive keys -> ds_write_b64 into shared P [q][key]
#pragma unroll
            for (int qs = 0; qs < 2; ++qs) {
                bf16* Pq = &Ps[(qh * 32 + qs * 16 + col) * 136 + kh * 64];
#pragma unroll
                for (int nt = 0; nt < 4; ++nt) {
                    bf16x4 pw;
#pragma unroll
                    for (int r = 0; r < 4; ++r)
                        pw[r] = (bf16)__builtin_amdgcn_exp2f(sv[qs][nt][r]);
                    *reinterpret_cast<bf16x4*>(&Pq[nt * 16 + quad * 4]) = pw;
                }
            }

            __syncthreads();   // P quadrants from all waves visible

            // PV: o[q-half qh][d-half kh] over all 128 keys; vb shared by 2 q-subs
            __builtin_amdgcn_s_setprio(1);
#pragma unroll
            for (int kg = 0; kg < 4; ++kg) {
                bf16x8 pa0 = *reinterpret_cast<const bf16x8*>(
                    &Ps[(qh * 32 + col) * 136 + kg * 32 + quad * 8]);
                bf16x8 pa1 = *reinterpret_cast<const bf16x8*>(
                    &Ps[(qh * 32 + 16 + col) * 136 + kg * 32 + quad * 8]);
                la[0] = MFMA16(pa0, ones, la[0]);
                la[1] = MFMA16(pa1, ones, la[1]);
#pragma unroll
                for (int dt = 0; dt < 2; ++dt) {
                    bf16x8 vb = *reinterpret_cast<const bf16x8*>(
                        &Vs[(kh * 32 + dt * 16 + col) * 128 + ((kg * 4 + quad) ^ col) * 8]);
                    o[0][dt] = MFMA16(pa0, vb, o[0][dt]);
                    o[1][dt] = MFMA16(pa1, vb, o[1][dt]);
                }
            }
            __builtin_amdgcn_s_setprio(0);
        }

#pragma unroll
        for (int qs = 0; qs < 2; ++qs) {
#pragma unroll
            for (int r = 0; r < 4; ++r) {
                int q = q0 + qh * 32 + qs * 16 + quad * 4 + r;
                float inv = __builtin_amdgcn_rcpf(la[qs][r]);
#pragma unroll
                for (int dt = 0; dt < 2; ++dt) {
                    int d = kh * 32 + dt * 16 + col;
                    out[((size_t)b * 2048 + q) * 1024 + h * 64 + d] = o[qs][dt][r] * inv;
                }
            }
        }
    }
}

extern "C" void kernel_launch(void* const* d_in, const int* in_sizes, int n_in,
                              void* d_out, int out_size, void* d_ws, size_t ws_size,
                              hipStream_t stream) {
    const float* x  = (const float*)d_in[0];
    const float* Wq = (const float*)d_in[1];
    const float* Wk = (const float*)d_in[2];
    const float* Wv = (const float*)d_in[3];
    float* out = (float*)d_out;

    char* ws = (char*)d_ws;
    bf16*  xb   = (bf16*)(ws);                        // 8 MB
    bf16*  wb   = (bf16*)(ws + (size_t)(8  << 20));   // 6 MB [Wq|Wk|Wv]
    bf16*  Qb   = (bf16*)(ws + (size_t)(14 << 20));   // 8 MB [B,H,S,D] (pre-scaled)
    bf16*  Kb   = (bf16*)(ws + (size_t)(22 << 20));   // 8 MB [B,H,S,D]
    bf16*  Vtb  = (bf16*)(ws + (size_t)(30 << 20));   // 8 MB [B,H,D,S]
    float* Tail = (float*)(ws + (size_t)(38 << 20));  // 264 KB

    const float QSCALE = 1.44269504088896f / 32.0f;   // log2(e)/sqrt(E)

    cast_all<<<7168, 256, 0, stream>>>(x, Wq, Wk, Wv, xb, wb, QSCALE);

    qkv_gemm<<<768, 256, 0, stream>>>(xb, wb, Qb, Kb, Vtb);

    tail_kernel<<<256, 256, 0, stream>>>(Vtb, Tail);

    attn_kernel<<<512, 256, 0, stream>>>(Qb, Kb, Vtb, Tail, out);
}